// Round 18
// baseline (88.849 us; speedup 1.0000x reference)
//
#include <hip/hip_runtime.h>

typedef float f32x4 __attribute__((ext_vector_type(4)));
typedef short bf16x8 __attribute__((ext_vector_type(8)));
typedef unsigned int u32;
typedef unsigned short u16;

constexpr int T_ = 32768;
constexpr int D_ = 2048;
constexpr int E_ = 64;
constexpr int KSEL = 6;
constexpr float ROUTE_SCALE_ = 1.0f;

constexpr int ROWS = 64;
constexpr int DK = 32;
constexpr int NCHH = 1024 / DK;     // 32 chunks per K-half
constexpr int WBUF = 12288;         // one W chunk: 12 frags x 1KB
constexpr int HSTRIDE = 2 * WBUF;   // fallback kernel: per-half dbuf
constexpr int SLSTR = 66;

constexpr size_t WSPLIT_BYTES = 64 * (size_t)WBUF;          // 786432
constexpr size_t P_HALF = (size_t)E_ * T_;                  // floats per half-plane
constexpr size_t WS_NEEDED = WSPLIT_BYTES + 2 * P_HALF * 4; // 17563648

__device__ __forceinline__ u16 f2bf(float f) {
  u32 u = __float_as_uint(f);
  return (u16)((u + 0x7fffu + ((u >> 16) & 1u)) >> 16);
}
__device__ __forceinline__ float bf2f(u16 h) { return __uint_as_float(((u32)h) << 16); }

// ---- W pre-split (bytes identical to R10/R12/R16) ----
__global__ void wsplit_kernel(const float* __restrict__ W, char* __restrict__ ws) {
  int g = blockIdx.x * 256 + threadIdx.x;
  if (g >= 64 * 256) return;
  int lane = g & 63, nfq = (g >> 6) & 3, c2 = g >> 8;
  int e = nfq * 16 + (lane & 15);
  int k0 = c2 * 32 + ((lane >> 4) << 3);
  const float* src = W + (size_t)e * D_ + k0;
  f32x4 a0 = *(const f32x4*)src;
  f32x4 a1 = *(const f32x4*)(src + 4);
  float f[8] = {a0.x, a0.y, a0.z, a0.w, a1.x, a1.y, a1.z, a1.w};
  bf16x8 h, m, l;
#pragma unroll
  for (int j = 0; j < 8; ++j) {
    u16 hb = f2bf(f[j]); float r1 = f[j] - bf2f(hb);
    u16 mb = f2bf(r1);   float r2 = r1 - bf2f(mb);
    u16 lb = f2bf(r2);
    h[j] = (short)hb; m[j] = (short)mb; l[j] = (short)lb;
  }
  char* dst = ws + (size_t)c2 * WBUF + (size_t)(nfq * 3) * 1024 + lane * 16;
  *(bf16x8*)(dst)        = h;
  *(bf16x8*)(dst + 1024) = m;
  *(bf16x8*)(dst + 2048) = l;
}

__device__ __forceinline__ void gload16(const void* g, void* l) {
  __builtin_amdgcn_global_load_lds(
      (const __attribute__((address_space(1))) void*)g,
      (__attribute__((address_space(3))) void*)l, 16, 0, 0);
}

// FROZEN numerics: truncation x-split + 6-product MFMA chain (R12/R16 bits).
#define XLOAD(BANK, C)                                            \
  { const float* p_ = xp + (size_t)(C) * DK;                      \
    BANK[0] = *(const f32x4*)(p_); BANK[1] = *(const f32x4*)(p_ + 4); }

#define STEP(BANK, C, WBASE)                                                   \
  {                                                                            \
    bf16x8 ah, am, al;                                                         \
    {                                                                          \
      f32x4 a0 = BANK[0], a1 = BANK[1];                                        \
      float f[8] = {a0.x, a0.y, a0.z, a0.w, a1.x, a1.y, a1.z, a1.w};           \
      _Pragma("unroll")                                                        \
      for (int j = 0; j < 8; ++j) {                                            \
        float v = f[j];                                                        \
        u32 uh = __float_as_uint(v) & 0xffff0000u;                             \
        float r1 = v - __uint_as_float(uh);                                    \
        u32 um = __float_as_uint(r1) & 0xffff0000u;                            \
        float r2 = r1 - __uint_as_float(um);                                   \
        u32 ul = __float_as_uint(r2);                                          \
        ah[j] = (short)(uh >> 16);                                             \
        am[j] = (short)(um >> 16);                                             \
        al[j] = (short)(ul >> 16);                                             \
      }                                                                        \
    }                                                                          \
    const char* wb = (WBASE) + ((C) & 1) * WBUF + lane * 16;                   \
    __builtin_amdgcn_s_setprio(1);                                             \
    _Pragma("unroll")                                                          \
    for (int n = 0; n < 4; ++n) {                                              \
      const char* fb = wb + (size_t)(n * 3) * 1024;                            \
      bf16x8 bh = *(const bf16x8*)(fb);                                        \
      bf16x8 bm = *(const bf16x8*)(fb + 1024);                                 \
      bf16x8 bl = *(const bf16x8*)(fb + 2048);                                 \
      f32x4 c_ = acc[n];                                                       \
      c_ = __builtin_amdgcn_mfma_f32_16x16x32_bf16(al, bh, c_, 0, 0, 0);       \
      c_ = __builtin_amdgcn_mfma_f32_16x16x32_bf16(am, bm, c_, 0, 0, 0);       \
      c_ = __builtin_amdgcn_mfma_f32_16x16x32_bf16(ah, bl, c_, 0, 0, 0);       \
      c_ = __builtin_amdgcn_mfma_f32_16x16x32_bf16(am, bh, c_, 0, 0, 0);       \
      c_ = __builtin_amdgcn_mfma_f32_16x16x32_bf16(ah, bm, c_, 0, 0, 0);       \
      c_ = __builtin_amdgcn_mfma_f32_16x16x32_bf16(ah, bh, c_, 0, 0, 0);       \
      acc[n] = c_;                                                             \
    }                                                                          \
    __builtin_amdgcn_s_setprio(0);                                             \
  }

// ---- NEW: per-half partial kernel. 4-wave blocks, grid = (T/64)*2 = 1024.
// Same chunk order / STEP bits as R16's halves -> partials bit-identical. ----
__launch_bounds__(256, 4)
__global__ void gate_partial(const float* __restrict__ x, const char* __restrict__ ws,
                             float* __restrict__ P) {
  __shared__ __align__(16) char sm[2 * WBUF];   // 24576 -> 4+ blocks/CU

  const int tid = threadIdx.x;
  const int lane = tid & 63;
  const int wl = tid >> 6;                 // 0..3, rows [wl*16, wl*16+16)
  const int half = blockIdx.x & 1;
  const int r0 = (blockIdx.x >> 1) * ROWS;

  const float* xp = x + (size_t)(r0 + wl * 16 + (lane & 15)) * D_
                      + half * 1024 + ((lane >> 4) << 3);

  f32x4 xA[2], xB[2];

  auto wgload = [&](int c2) {
    const char* src = ws + (size_t)(half * NCHH + c2) * WBUF
                         + (size_t)(wl * 64 + lane) * 16;               // per-lane
    char* dstb = sm + (c2 & 1) * WBUF + (size_t)(wl * 64) * 16;         // wave-uniform
#pragma unroll
    for (int it = 0; it < 3; ++it)
      gload16(src + it * 4096, dstb + it * 4096);
  };

  f32x4 acc[4] = {};

  XLOAD(xA, 0)
  XLOAD(xB, 1)
  wgload(0);

  for (int cc = 0; cc < NCHH; cc += 2) {
    __syncthreads();
    if (cc + 1 < NCHH) wgload(cc + 1);
    STEP(xA, cc, sm)
    if (cc + 2 < NCHH) XLOAD(xA, cc + 2)
    __syncthreads();
    if (cc + 2 < NCHH) wgload(cc + 2);
    STEP(xB, cc + 1, sm)
    if (cc + 3 < NCHH) XLOAD(xB, cc + 3)
  }

  // transpose partials via LDS (as R16), then coalesced store P[half][e][r0+lane]
  __syncthreads();
  float* SL = (float*)sm;
#pragma unroll
  for (int n = 0; n < 4; ++n)
#pragma unroll
    for (int j = 0; j < 4; ++j) {
      int r = wl * 16 + ((lane >> 4) << 2) + j;
      int e = n * 16 + (lane & 15);
      SL[e * SLSTR + r] = acc[n][j];
    }
  __syncthreads();
  float* Pg = P + (size_t)half * P_HALF + r0 + lane;
#pragma unroll
  for (int ee = 0; ee < 16; ++ee) {
    int e = wl * 16 + ee;
    Pg[(size_t)e * T_] = SL[e * SLSTR + lane];
  }
}

// ---- NEW: reduce halves (h0 + h1, same order as R16's epilogue -> identical bits)
// + proven insertion top-k. ----
__launch_bounds__(128)
__global__ void reduce_topk(const float* __restrict__ P, float* __restrict__ out) {
  const int r = blockIdx.x * 128 + threadIdx.x;
  float tv[KSEL], ti[KSEL];
#pragma unroll
  for (int kk = 0; kk < KSEL; ++kk) { tv[kk] = -3.4e38f; ti[kk] = 0.f; }
  for (int e = 0; e < E_; ++e) {
    float v = P[(size_t)e * T_ + r] + P[P_HALF + (size_t)e * T_ + r];
    float vi = (float)e;
#pragma unroll
    for (int kk = 0; kk < KSEL; ++kk) {
      bool c = v > tv[kk];
      float nv = c ? v : tv[kk];  float dv = c ? tv[kk] : v;
      float ni = c ? vi : ti[kk]; float di = c ? ti[kk] : vi;
      tv[kk] = nv; v = dv; ti[kk] = ni; vi = di;
    }
  }
  float* outI = out;
  float* outW = out + (size_t)T_ * KSEL;
#pragma unroll
  for (int kk = 0; kk < KSEL; ++kk) {
    outI[(size_t)r * KSEL + kk] = ti[kk];
    outW[(size_t)r * KSEL + kk] = tv[kk] * ROUTE_SCALE_;
  }
}

// ---- FALLBACK: R16 kernel verbatim (used if ws too small for P) ----
__launch_bounds__(512, 4)
__global__ void gate_kernel(const float* __restrict__ x, const char* __restrict__ ws,
                            float* __restrict__ out) {
  __shared__ __align__(16) char sm[2 * HSTRIDE];

  const int tid = threadIdx.x;
  const int lane = tid & 63;
  const int wv = tid >> 6;
  const int half = wv >> 2;
  const int wl = wv & 3;
  const int r0 = blockIdx.x * ROWS;

  const float* xp = x + (size_t)(r0 + wl * 16 + (lane & 15)) * D_
                      + half * 1024 + ((lane >> 4) << 3);

  f32x4 xA[2], xB[2];

  auto wgload = [&](int c2) {
    const char* src = ws + (size_t)(half * NCHH + c2) * WBUF
                         + (size_t)(wl * 64 + lane) * 16;
    char* dstb = sm + half * HSTRIDE + (c2 & 1) * WBUF + (size_t)(wl * 64) * 16;
#pragma unroll
    for (int it = 0; it < 3; ++it)
      gload16(src + it * 4096, dstb + it * 4096);
  };

  f32x4 acc[4] = {};
  char* wbase = sm + half * HSTRIDE;

  XLOAD(xA, 0)
  XLOAD(xB, 1)
  wgload(0);

  for (int cc = 0; cc < NCHH; cc += 2) {
    __syncthreads();
    if (cc + 1 < NCHH) wgload(cc + 1);
    STEP(xA, cc, wbase)
    if (cc + 2 < NCHH) XLOAD(xA, cc + 2)
    __syncthreads();
    if (cc + 2 < NCHH) wgload(cc + 2);
    STEP(xB, cc + 1, wbase)
    if (cc + 3 < NCHH) XLOAD(xB, cc + 3)
  }

  __syncthreads();
  float* SL = (float*)sm;
#pragma unroll
  for (int n = 0; n < 4; ++n)
#pragma unroll
    for (int j = 0; j < 4; ++j) {
      int r = wl * 16 + ((lane >> 4) << 2) + j;
      int e = n * 16 + (lane & 15);
      SL[half * (E_ * SLSTR) + e * SLSTR + r] = acc[n][j];
    }
  __syncthreads();

  if (wv == 0) {
    float tv[KSEL], ti[KSEL];
#pragma unroll
    for (int kk = 0; kk < KSEL; ++kk) { tv[kk] = -3.4e38f; ti[kk] = 0.f; }
    for (int e = 0; e < E_; ++e) {
      float v = SL[e * SLSTR + lane] + SL[E_ * SLSTR + e * SLSTR + lane];
      float vi = (float)e;
#pragma unroll
      for (int kk = 0; kk < KSEL; ++kk) {
        bool c = v > tv[kk];
        float nv = c ? v : tv[kk];  float dv = c ? tv[kk] : v;
        float ni = c ? vi : ti[kk]; float di = c ? ti[kk] : vi;
        tv[kk] = nv; v = dv; ti[kk] = ni; vi = di;
      }
    }
    const int rg = r0 + lane;
    float* outI = out;
    float* outW = out + (size_t)T_ * KSEL;
#pragma unroll
    for (int kk = 0; kk < KSEL; ++kk) {
      outI[(size_t)rg * KSEL + kk] = ti[kk];
      outW[(size_t)rg * KSEL + kk] = tv[kk] * ROUTE_SCALE_;
    }
  }
}

extern "C" void kernel_launch(void* const* d_in, const int* in_sizes, int n_in,
                              void* d_out, int out_size, void* d_ws, size_t ws_size,
                              hipStream_t stream) {
  const float* x = (const float*)d_in[0];
  const float* W = (const float*)d_in[1];
  char* ws = (char*)d_ws;
  float* out = (float*)d_out;
  wsplit_kernel<<<dim3(64), dim3(256), 0, stream>>>(W, ws);
  if (ws_size >= WS_NEEDED) {
    float* P = (float*)(ws + WSPLIT_BYTES);
    gate_partial<<<dim3(T_ / ROWS * 2), dim3(256), 0, stream>>>(x, ws, P);
    reduce_topk<<<dim3(T_ / 128), dim3(128), 0, stream>>>(P, out);
  } else {
    gate_kernel<<<dim3(T_ / ROWS), dim3(512), 0, stream>>>(x, ws, out);
  }
}

// Round 19
// 74.940 us; speedup vs baseline: 1.1856x; 1.1856x over previous
//
#include <hip/hip_runtime.h>

typedef float f32x4 __attribute__((ext_vector_type(4)));
typedef short bf16x8 __attribute__((ext_vector_type(8)));
typedef unsigned int u32;
typedef unsigned short u16;

constexpr int T_ = 32768;
constexpr int D_ = 2048;
constexpr int E_ = 64;
constexpr int KSEL = 6;
constexpr float ROUTE_SCALE_ = 1.0f;

constexpr int ROWS = 64;            // rows per block; 8 waves = 2 rg(32 rows) x 4 K-quarters
constexpr int DK = 32;              // k per chunk
constexpr int QCH = 16;             // chunks per K-quarter (512 k)
constexpr int WBUF = 12288;         // one W chunk: 12 frags x 1KB
constexpr int SLSTR = 66;           // SL plane: [64 e][66] floats = 16896 B

__device__ __forceinline__ u16 f2bf(float f) {
  u32 u = __float_as_uint(f);
  return (u16)((u + 0x7fffu + ((u >> 16) & 1u)) >> 16);
}
__device__ __forceinline__ float bf2f(u16 h) { return __uint_as_float(((u32)h) << 16); }

// ---- W pre-split (bytes identical to R10/R12/R16) ----
__global__ void wsplit_kernel(const float* __restrict__ W, char* __restrict__ ws) {
  int g = blockIdx.x * 256 + threadIdx.x;
  if (g >= 64 * 256) return;
  int lane = g & 63, nfq = (g >> 6) & 3, c2 = g >> 8;
  int e = nfq * 16 + (lane & 15);
  int k0 = c2 * 32 + ((lane >> 4) << 3);
  const float* src = W + (size_t)e * D_ + k0;
  f32x4 a0 = *(const f32x4*)src;
  f32x4 a1 = *(const f32x4*)(src + 4);
  float f[8] = {a0.x, a0.y, a0.z, a0.w, a1.x, a1.y, a1.z, a1.w};
  bf16x8 h, m, l;
#pragma unroll
  for (int j = 0; j < 8; ++j) {
    u16 hb = f2bf(f[j]); float r1 = f[j] - bf2f(hb);   // exact
    u16 mb = f2bf(r1);   float r2 = r1 - bf2f(mb);     // exact
    u16 lb = f2bf(r2);
    h[j] = (short)hb; m[j] = (short)mb; l[j] = (short)lb;
  }
  char* dst = ws + (size_t)c2 * WBUF + (size_t)(nfq * 3) * 1024 + lane * 16;
  *(bf16x8*)(dst)        = h;
  *(bf16x8*)(dst + 1024) = m;
  *(bf16x8*)(dst + 2048) = l;
}

__device__ __forceinline__ void gload16(const void* g, void* l) {
  __builtin_amdgcn_global_load_lds(
      (const __attribute__((address_space(1))) void*)g,
      (__attribute__((address_space(3))) void*)l, 16, 0, 0);
}

__launch_bounds__(512, 4)
__global__ void gate_kernel(const float* __restrict__ x, const char* __restrict__ ws,
                            float* __restrict__ out) {
  __shared__ __align__(16) char sm[4 * WBUF];   // 49152 B -> 2 blocks/CU

  const int tid = threadIdx.x;
  const int lane = tid & 63;
  const int wv = tid >> 6;                 // 0..7
  const int rg = wv & 1;                   // rowgroup: rows [rg*32, rg*32+32)
  const int q  = wv >> 1;                  // K-quarter: k in [q*512, q*512+512)
  const int r0 = blockIdx.x * ROWS;

  // per-lane x base: rows r0+rg*32+(lane&15) (+16 for mf=1), k = q*512 + (lane>>4)*8
  const float* xp = x + (size_t)(r0 + rg * 32 + (lane & 15)) * D_
                      + q * 512 + ((lane >> 4) << 3);

  f32x4 xA[4], xB[4];   // bank = 4 f32x4: [0,1]=row r k0..7 ; [2,3]=row r+16

#define XLOAD(BANK, C)                                                        \
  { const float* p_ = xp + (size_t)(C) * DK;                                  \
    BANK[0] = *(const f32x4*)(p_);           BANK[1] = *(const f32x4*)(p_ + 4); \
    BANK[2] = *(const f32x4*)(p_ + 16 * D_); BANK[3] = *(const f32x4*)(p_ + 16 * D_ + 4); }

  // single-buffered per-quarter W staging: 2 waves (rg 0/1) x 6 gload16 = 12KB.
  // LDS dst wave-uniform (HW adds lane*16); global src per-lane, identity map.
  char* qbuf = sm + q * WBUF;
  auto stage = [&](int c2) {
    const char* src = ws + (size_t)(q * QCH + c2) * WBUF
                         + (size_t)(rg * 6144 + lane * 16);
    char* dstb = qbuf + (size_t)rg * 6144;
#pragma unroll
    for (int it = 0; it < 6; ++it)
      gload16(src + it * 1024, dstb + it * 1024);
  };

  f32x4 acc[2][4] = {};                    // [mf][expert-quadrant n]

  // FROZEN per-accumulator chain (R12/R16 bits per quarter); B reads shared by mf.
#define STEP(BANK)                                                             \
  {                                                                            \
    bf16x8 ah[2], am[2], al[2];                                                \
    _Pragma("unroll")                                                          \
    for (int mf = 0; mf < 2; ++mf) {                                           \
      f32x4 a0 = BANK[2 * mf], a1 = BANK[2 * mf + 1];                          \
      float f[8] = {a0.x, a0.y, a0.z, a0.w, a1.x, a1.y, a1.z, a1.w};           \
      _Pragma("unroll")                                                        \
      for (int j = 0; j < 8; ++j) {                                            \
        float v = f[j];                                                        \
        u32 uh = __float_as_uint(v) & 0xffff0000u;                             \
        float r1 = v - __uint_as_float(uh);                                    \
        u32 um = __float_as_uint(r1) & 0xffff0000u;                            \
        float r2 = r1 - __uint_as_float(um);                                   \
        u32 ul = __float_as_uint(r2);                                          \
        ah[mf][j] = (short)(uh >> 16);                                         \
        am[mf][j] = (short)(um >> 16);                                         \
        al[mf][j] = (short)(ul >> 16);                                         \
      }                                                                        \
    }                                                                          \
    const char* wb = qbuf + lane * 16;                                         \
    _Pragma("unroll")                                                          \
    for (int n = 0; n < 4; ++n) {                                              \
      const char* fb = wb + (size_t)(n * 3) * 1024;                            \
      bf16x8 bh = *(const bf16x8*)(fb);                                        \
      bf16x8 bm = *(const bf16x8*)(fb + 1024);                                 \
      bf16x8 bl = *(const bf16x8*)(fb + 2048);                                 \
      _Pragma("unroll")                                                        \
      for (int mf = 0; mf < 2; ++mf) {                                         \
        f32x4 c_ = acc[mf][n];                                                 \
        c_ = __builtin_amdgcn_mfma_f32_16x16x32_bf16(al[mf], bh, c_, 0, 0, 0); \
        c_ = __builtin_amdgcn_mfma_f32_16x16x32_bf16(am[mf], bm, c_, 0, 0, 0); \
        c_ = __builtin_amdgcn_mfma_f32_16x16x32_bf16(ah[mf], bl, c_, 0, 0, 0); \
        c_ = __builtin_amdgcn_mfma_f32_16x16x32_bf16(am[mf], bh, c_, 0, 0, 0); \
        c_ = __builtin_amdgcn_mfma_f32_16x16x32_bf16(ah[mf], bm, c_, 0, 0, 0); \
        c_ = __builtin_amdgcn_mfma_f32_16x16x32_bf16(ah[mf], bh, c_, 0, 0, 0); \
        acc[mf][n] = c_;                                                       \
      }                                                                        \
    }                                                                          \
  }

  // prologue: x chunk 0 to bank A; W chunk 0 staged
  XLOAD(xA, 0)
  stage(0);

  // main loop, single-buffered W: per chunk {bar(staged) ; xload(c+1) ; STEP(c) ;
  // bar(reads done) ; stage(c+1)}. XLOAD covered by STEP; stage covered by the
  // co-resident block.
  for (int cc = 0; cc < QCH; cc += 2) {
    __syncthreads();
    if (cc + 1 < QCH) XLOAD(xB, cc + 1)
    STEP(xA)
    __syncthreads();
    if (cc + 1 < QCH) stage(cc + 1);
    __syncthreads();
    if (cc + 2 < QCH) XLOAD(xA, cc + 2)
    STEP(xB)
    __syncthreads();
    if (cc + 2 < QCH) stage(cc + 2);
  }

  // ---- pairwise quarter reduction in LDS (reuses W region; all reads done).
  // logit = (q0+q2) + (q1+q3): plane p=q for q<2 (write), p=q-2 for q>=2 (add). ----
  __syncthreads();
  float* SL = (float*)sm;                  // 2 planes x [64 e][66] floats
  if (q < 2) {
#pragma unroll
    for (int mf = 0; mf < 2; ++mf)
#pragma unroll
      for (int n = 0; n < 4; ++n)
#pragma unroll
        for (int j = 0; j < 4; ++j) {
          int r = rg * 32 + mf * 16 + ((lane >> 4) << 2) + j;
          int e = n * 16 + (lane & 15);
          SL[q * (E_ * SLSTR) + e * SLSTR + r] = acc[mf][n][j];
        }
  }
  __syncthreads();
  if (q >= 2) {
#pragma unroll
    for (int mf = 0; mf < 2; ++mf)
#pragma unroll
      for (int n = 0; n < 4; ++n)
#pragma unroll
        for (int j = 0; j < 4; ++j) {
          int r = rg * 32 + mf * 16 + ((lane >> 4) << 2) + j;
          int e = n * 16 + (lane & 15);
          SL[(q - 2) * (E_ * SLSTR) + e * SLSTR + r] += acc[mf][n][j];
        }
  }
  __syncthreads();

  // ---- softmax-free top-k (R16-proven): wave 0, lane = row; strict > +
  // ascending-e scan == jax tie-to-lower-index. ----
  if (wv == 0) {
    float tv[KSEL], ti[KSEL];
#pragma unroll
    for (int kk = 0; kk < KSEL; ++kk) { tv[kk] = -3.4e38f; ti[kk] = 0.f; }
    for (int e = 0; e < E_; ++e) {
      float v = SL[e * SLSTR + lane] + SL[E_ * SLSTR + e * SLSTR + lane];
      float vi = (float)e;
#pragma unroll
      for (int kk = 0; kk < KSEL; ++kk) {
        bool c = v > tv[kk];
        float nv = c ? v : tv[kk];  float dv = c ? tv[kk] : v;
        float ni = c ? vi : ti[kk]; float di = c ? ti[kk] : vi;
        tv[kk] = nv; v = dv; ti[kk] = ni; vi = di;
      }
    }
    const int rg2 = r0 + lane;
    float* outI = out;
    float* outW = out + (size_t)T_ * KSEL;
#pragma unroll
    for (int kk = 0; kk < KSEL; ++kk) {
      outI[(size_t)rg2 * KSEL + kk] = ti[kk];
      outW[(size_t)rg2 * KSEL + kk] = tv[kk] * ROUTE_SCALE_;
    }
  }
#undef XLOAD
#undef STEP
}

extern "C" void kernel_launch(void* const* d_in, const int* in_sizes, int n_in,
                              void* d_out, int out_size, void* d_ws, size_t ws_size,
                              hipStream_t stream) {
  const float* x = (const float*)d_in[0];
  const float* W = (const float*)d_in[1];
  char* ws = (char*)d_ws;                  // 64 * 12288 = 786432 bytes
  float* out = (float*)d_out;
  wsplit_kernel<<<dim3(64), dim3(256), 0, stream>>>(W, ws);
  gate_kernel<<<dim3(T_ / ROWS), dim3(512), 0, stream>>>(x, ws, out);
}

// Round 21
// 72.467 us; speedup vs baseline: 1.2261x; 1.0341x over previous
//
#include <hip/hip_runtime.h>

typedef float f32x4 __attribute__((ext_vector_type(4)));
typedef short bf16x8 __attribute__((ext_vector_type(8)));
typedef unsigned int u32;
typedef unsigned short u16;

constexpr int T_ = 32768;
constexpr int D_ = 2048;
constexpr int E_ = 64;
constexpr int KSEL = 6;
constexpr float ROUTE_SCALE_ = 1.0f;

constexpr int ROWS = 64;            // rows per block; 8 waves = 4 rg x 2 K-halves
constexpr int DK = 32;              // k per chunk
constexpr int NCHH = 1024 / DK;     // 32 chunks per K-half
constexpr int WBUF = 12288;         // one W chunk: 12 frags x 1KB
constexpr int HSTRIDE = 2 * WBUF;   // per-half dbuf; LDS total = 49152
constexpr int SLSTR = 66;           // padded row-stride of SL[half][e][row]

__device__ __forceinline__ u16 f2bf(float f) {
  u32 u = __float_as_uint(f);
  return (u16)((u + 0x7fffu + ((u >> 16) & 1u)) >> 16);
}
__device__ __forceinline__ float bf2f(u16 h) { return __uint_as_float(((u32)h) << 16); }

// ---- W pre-split (bytes identical to R10/R12/R16 lineage) ----
__global__ void wsplit_kernel(const float* __restrict__ W, char* __restrict__ ws) {
  int g = blockIdx.x * 256 + threadIdx.x;
  if (g >= 64 * 256) return;                   // 16384 threads
  int lane = g & 63, nfq = (g >> 6) & 3, c2 = g >> 8;
  int e = nfq * 16 + (lane & 15);
  int k0 = c2 * 32 + ((lane >> 4) << 3);
  const float* src = W + (size_t)e * D_ + k0;
  f32x4 a0 = *(const f32x4*)src;
  f32x4 a1 = *(const f32x4*)(src + 4);
  float f[8] = {a0.x, a0.y, a0.z, a0.w, a1.x, a1.y, a1.z, a1.w};
  bf16x8 h, m, l;
#pragma unroll
  for (int j = 0; j < 8; ++j) {
    u16 hb = f2bf(f[j]); float r1 = f[j] - bf2f(hb);   // exact
    u16 mb = f2bf(r1);   float r2 = r1 - bf2f(mb);     // exact
    u16 lb = f2bf(r2);
    h[j] = (short)hb; m[j] = (short)mb; l[j] = (short)lb;
  }
  char* dst = ws + (size_t)c2 * WBUF + (size_t)(nfq * 3) * 1024 + lane * 16;
  *(bf16x8*)(dst)        = h;
  *(bf16x8*)(dst + 1024) = m;
  *(bf16x8*)(dst + 2048) = l;
}

__device__ __forceinline__ void gload16(const void* g, void* l) {
  __builtin_amdgcn_global_load_lds(
      (const __attribute__((address_space(1))) void*)g,
      (__attribute__((address_space(3))) void*)l, 16, 0, 0);
}

__launch_bounds__(512, 4)
__global__ void gate_kernel(const float* __restrict__ x, const char* __restrict__ ws,
                            float* __restrict__ out) {
  __shared__ __align__(16) char sm[2 * HSTRIDE];   // 49152 B

  const int tid = threadIdx.x;
  const int lane = tid & 63;
  const int wv = tid >> 6;                 // 0..7
  const int half = wv >> 2;                // K-half: k in [half*1024, +1024)
  const int wl = wv & 3;                   // row group: rows [wl*16, wl*16+16)
  const int r0 = blockIdx.x * ROWS;

  const float* xp = x + (size_t)(r0 + wl * 16 + (lane & 15)) * D_
                      + half * 1024 + ((lane >> 4) << 3);

  f32x4 xA[2], xB[2];                      // two static reg banks (chunk c, c+1)

#define XLOAD(BANK, C)                                            \
  { const float* p_ = xp + (size_t)(C) * DK;                      \
    BANK[0] = *(const f32x4*)(p_); BANK[1] = *(const f32x4*)(p_ + 4); }

  auto wgload = [&](int c2) {
    const char* src = ws + (size_t)(half * NCHH + c2) * WBUF
                         + (size_t)(wl * 64 + lane) * 16;               // per-lane
    char* dstb = sm + half * HSTRIDE + (c2 & 1) * WBUF + (size_t)(wl * 64) * 16;  // uniform
#pragma unroll
    for (int it = 0; it < 3; ++it)
      gload16(src + it * 4096, dstb + it * 4096);
  };

  f32x4 acc[4] = {};                       // 4 expert-quadrants x 4 regs

  // FROZEN numerics: truncation x-split + 6-product MFMA chain (R12/R16 bits)
#define STEP(BANK, C)                                                          \
  {                                                                            \
    bf16x8 ah, am, al;                                                         \
    {                                                                          \
      f32x4 a0 = BANK[0], a1 = BANK[1];                                        \
      float f[8] = {a0.x, a0.y, a0.z, a0.w, a1.x, a1.y, a1.z, a1.w};           \
      _Pragma("unroll")                                                        \
      for (int j = 0; j < 8; ++j) {                                            \
        float v = f[j];                                                        \
        u32 uh = __float_as_uint(v) & 0xffff0000u;                             \
        float r1 = v - __uint_as_float(uh);                                    \
        u32 um = __float_as_uint(r1) & 0xffff0000u;                            \
        float r2 = r1 - __uint_as_float(um);                                   \
        u32 ul = __float_as_uint(r2);                                          \
        ah[j] = (short)(uh >> 16);                                             \
        am[j] = (short)(um >> 16);                                             \
        al[j] = (short)(ul >> 16);                                             \
      }                                                                        \
    }                                                                          \
    const char* wb = sm + half * HSTRIDE + ((C) & 1) * WBUF + lane * 16;       \
    _Pragma("unroll")                                                          \
    for (int n = 0; n < 4; ++n) {                                              \
      const char* fb = wb + (size_t)(n * 3) * 1024;                            \
      bf16x8 bh = *(const bf16x8*)(fb);                                        \
      bf16x8 bm = *(const bf16x8*)(fb + 1024);                                 \
      bf16x8 bl = *(const bf16x8*)(fb + 2048);                                 \
      f32x4 c_ = acc[n];                                                       \
      c_ = __builtin_amdgcn_mfma_f32_16x16x32_bf16(al, bh, c_, 0, 0, 0);       \
      c_ = __builtin_amdgcn_mfma_f32_16x16x32_bf16(am, bm, c_, 0, 0, 0);       \
      c_ = __builtin_amdgcn_mfma_f32_16x16x32_bf16(ah, bl, c_, 0, 0, 0);       \
      c_ = __builtin_amdgcn_mfma_f32_16x16x32_bf16(am, bh, c_, 0, 0, 0);       \
      c_ = __builtin_amdgcn_mfma_f32_16x16x32_bf16(ah, bm, c_, 0, 0, 0);       \
      c_ = __builtin_amdgcn_mfma_f32_16x16x32_bf16(ah, bh, c_, 0, 0, 0);       \
      acc[n] = c_;                                                             \
    }                                                                          \
  }

  // prologue + main loop: R12's schedule (best measured)
  XLOAD(xA, 0)
  XLOAD(xB, 1)
  wgload(0);

  for (int cc = 0; cc < NCHH; cc += 2) {
    __syncthreads();
    if (cc + 1 < NCHH) wgload(cc + 1);
    STEP(xA, cc)
    if (cc + 2 < NCHH) XLOAD(xA, cc + 2)
    __syncthreads();
    if (cc + 2 < NCHH) wgload(cc + 2);
    STEP(xB, cc + 1)
    if (cc + 3 < NCHH) XLOAD(xB, cc + 3)
  }

  // ---- partial logits TRANSPOSED to LDS: SL[half][e][row], stride 66 ----
  __syncthreads();                         // all STEP reads of wbuf done
  float* SL = (float*)sm;
#pragma unroll
  for (int n = 0; n < 4; ++n)
#pragma unroll
    for (int j = 0; j < 4; ++j) {
      int r = wl * 16 + ((lane >> 4) << 2) + j;
      int e = n * 16 + (lane & 15);
      SL[half * (E_ * SLSTR) + e * SLSTR + r] = acc[n][j];
    }
  __syncthreads();

  // ---- softmax-free top-k (monotone softmax => top-k by logit; strict > +
  // ascending-e scan == jax tie-to-lower-index). wave 0, lane = row. ----
  if (wv == 0) {
    float tv[KSEL], ti[KSEL];
#pragma unroll
    for (int kk = 0; kk < KSEL; ++kk) { tv[kk] = -3.4e38f; ti[kk] = 0.f; }
    for (int e = 0; e < E_; ++e) {
      float v = SL[e * SLSTR + lane] + SL[E_ * SLSTR + e * SLSTR + lane];
      float vi = (float)e;
#pragma unroll
      for (int kk = 0; kk < KSEL; ++kk) {
        bool c = v > tv[kk];
        float nv = c ? v : tv[kk];  float dv = c ? tv[kk] : v;
        float ni = c ? vi : ti[kk]; float di = c ? ti[kk] : vi;
        tv[kk] = nv; v = dv; ti[kk] = ni; vi = di;
      }
    }
    const int rg = r0 + lane;
    float* outI = out;
    float* outW = out + (size_t)T_ * KSEL;
#pragma unroll
    for (int kk = 0; kk < KSEL; ++kk) {
      outI[(size_t)rg * KSEL + kk] = ti[kk];
      outW[(size_t)rg * KSEL + kk] = tv[kk] * ROUTE_SCALE_;
    }
  }
#undef XLOAD
#undef STEP
}

extern "C" void kernel_launch(void* const* d_in, const int* in_sizes, int n_in,
                              void* d_out, int out_size, void* d_ws, size_t ws_size,
                              hipStream_t stream) {
  const float* x = (const float*)d_in[0];
  const float* W = (const float*)d_in[1];
  char* ws = (char*)d_ws;                  // 64 * 12288 = 786432 bytes
  float* out = (float*)d_out;
  wsplit_kernel<<<dim3(64), dim3(256), 0, stream>>>(W, ws);
  gate_kernel<<<dim3(T_ / ROWS), dim3(512), 0, stream>>>(x, ws, out);
}